// Round 1
// baseline (485.601 us; speedup 1.0000x reference)
//
#include <hip/hip_runtime.h>

// MultiHeadDiffAttention: B=2, T=2048, C=1024, H=16 (v-heads), 2H=32 (q/k heads),
// D=32, Dv=64. Pipeline: cvt -> transpose weights -> qkv GEMM (bf16 MFMA) ->
// RoPE -> flash attention -> diff+RMS -> out GEMM.

typedef unsigned short u16;
typedef __bf16 bf16x8 __attribute__((ext_vector_type(8)));
typedef float f32x4 __attribute__((ext_vector_type(4)));

__device__ __forceinline__ u16 f2bf(float f) {
  return __builtin_bit_cast(u16, (__bf16)f);
}
__device__ __forceinline__ float bf2f(u16 u) {
  return (float)__builtin_bit_cast(__bf16, u);
}

// ---------------------------------------------------------------- cvt x->bf16
__global__ __launch_bounds__(256) void cvt_f32_bf16(const float* __restrict__ in,
                                                    u16* __restrict__ out, int n4) {
  int i = blockIdx.x * 256 + threadIdx.x;
  if (i < n4) {
    float4 v = ((const float4*)in)[i];
    ushort4 o;
    o.x = f2bf(v.x); o.y = f2bf(v.y); o.z = f2bf(v.z); o.w = f2bf(v.w);
    ((ushort4*)out)[i] = o;
  }
}

// ------------------------------------------- transpose fp32 [R][Cn] -> bf16 [Cn][R]
__global__ __launch_bounds__(256) void transpose_f32_to_bf16(
    const float* __restrict__ in, u16* __restrict__ out, int R, int Cn) {
  __shared__ float tile[32][33];
  const int tx = threadIdx.x & 31, ty = threadIdx.x >> 5;  // ty 0..7
  const int c0 = blockIdx.x * 32, r0 = blockIdx.y * 32;
#pragma unroll
  for (int rr = 0; rr < 4; ++rr)
    tile[ty + rr * 8][tx] = in[(size_t)(r0 + ty + rr * 8) * Cn + c0 + tx];
  __syncthreads();
#pragma unroll
  for (int rr = 0; rr < 4; ++rr)
    out[(size_t)(c0 + ty + rr * 8) * R + r0 + tx] = f2bf(tile[tx][ty + rr * 8]);
}

// ---------------------------------------------------------------- bf16 GEMM
// A: [M][K] bf16 row-major; BT: [N][K] bf16 (B transposed); C: [M][N]
// 128x128 tile, K-step 32, 256 threads (4 waves, 2x2 of 64x64).
template <bool OUT_BF16>
__global__ __launch_bounds__(256) void gemm_bf16_kernel(
    const u16* __restrict__ A, const u16* __restrict__ BT, void* __restrict__ Cout,
    int Mdim, int Ndim, int Kdim) {
  __shared__ u16 As[128 * 32];
  __shared__ u16 Bs[128 * 32];
  const int tid = threadIdx.x;
  const int l = tid & 63;
  const int w = tid >> 6;
  const int bm = blockIdx.y, bn = blockIdx.x;
  const int wm = w >> 1, wn = w & 1;
  const int rowA0 = bm * 128, rowB0 = bn * 128;
  const int srow = l >> 2;         // 0..15
  const int skq = (l & 3) * 8;     // k element offset
  f32x4 acc[4][4] = {};
  for (int k0 = 0; k0 < Kdim; k0 += 32) {
#pragma unroll
    for (int c = 0; c < 2; ++c) {
      const int r = c * 64 + w * 16 + srow;
      *(uint4*)&As[r * 32 + skq] =
          *(const uint4*)&A[(size_t)(rowA0 + r) * Kdim + k0 + skq];
      *(uint4*)&Bs[r * 32 + skq] =
          *(const uint4*)&BT[(size_t)(rowB0 + r) * Kdim + k0 + skq];
    }
    __syncthreads();
    bf16x8 a[4], b[4];
#pragma unroll
    for (int i = 0; i < 4; ++i)
      a[i] = *(const bf16x8*)&As[(wm * 64 + i * 16 + (l & 15)) * 32 + (l >> 4) * 8];
#pragma unroll
    for (int j = 0; j < 4; ++j)
      b[j] = *(const bf16x8*)&Bs[(wn * 64 + j * 16 + (l & 15)) * 32 + (l >> 4) * 8];
#pragma unroll
    for (int i = 0; i < 4; ++i)
#pragma unroll
      for (int j = 0; j < 4; ++j)
        acc[i][j] = __builtin_amdgcn_mfma_f32_16x16x32_bf16(a[i], b[j], acc[i][j], 0, 0, 0);
    __syncthreads();
  }
  const int cr = (l >> 4) * 4;
  const int cc = l & 15;
#pragma unroll
  for (int i = 0; i < 4; ++i)
#pragma unroll
    for (int j = 0; j < 4; ++j)
#pragma unroll
      for (int r = 0; r < 4; ++r) {
        const int row = rowA0 + wm * 64 + i * 16 + cr + r;
        const int col = rowB0 + wn * 64 + j * 16 + cc;
        if (OUT_BF16)
          ((u16*)Cout)[(size_t)row * Ndim + col] = f2bf(acc[i][j][r]);
        else
          ((float*)Cout)[(size_t)row * Ndim + col] = acc[i][j][r];
      }
}

// ---------------------------------------------------------------- RoPE + layout
// qkv bf16 [4096][3072] -> Q,K bf16 (B,32,T,32) roped; V bf16 (B,16,T,64) copy.
__global__ __launch_bounds__(256) void rope_kernel(const u16* __restrict__ qkv,
                                                   u16* __restrict__ Q,
                                                   u16* __restrict__ K,
                                                   u16* __restrict__ V) {
  const int row = blockIdx.x;  // 0..4095
  const int b = row >> 11, t = row & 2047;
  const int tid = threadIdx.x;
  // q/k rope pairs: 512 each (head hh 0..31, pair i 0..15)
  for (int p = tid; p < 1024; p += 256) {
    const int isK = p >> 9;
    const int pp = p & 511;
    const int hh = pp >> 4;
    const int i = pp & 15;
    const size_t src = (size_t)row * 3072 + (size_t)isK * 1024 + hh * 32 + 2 * i;
    const float x1 = bf2f(qkv[src]), x2 = bf2f(qkv[src + 1]);
    const float theta = exp2f(-0.83048202372184059f * (float)i);  // 10000^(-i/16)
    const float ang = (float)t * theta;
    float sn, cs;
    sincosf(ang, &sn, &cs);
    ushort2 ov;
    ov.x = f2bf(x1 * cs - x2 * sn);
    ov.y = f2bf(x1 * sn + x2 * cs);
    u16* dst = isK ? K : Q;
    *(ushort2*)&dst[((size_t)(b * 32 + hh) * 2048 + t) * 32 + 2 * i] = ov;
  }
  // v copy: 1024 elems, 4 per thread
  {
    const int c2 = tid * 4;
    const int hv = c2 >> 6, dv = c2 & 63;
    *(ushort4*)&V[((size_t)(b * 16 + hv) * 2048 + t) * 64 + dv] =
        *(const ushort4*)&qkv[(size_t)row * 3072 + 2048 + c2];
  }
}

// ---------------------------------------------------------------- flash attention
// grid (T/64, 32 heads, B). 4 waves; wave w owns 16 q rows. KV step 32, causal.
__global__ __launch_bounds__(256) void attn_kernel(const u16* __restrict__ Q,
                                                   const u16* __restrict__ K,
                                                   const u16* __restrict__ V,
                                                   float* __restrict__ Aout) {
  __shared__ u16 Ks[32 * 32];
  __shared__ u16 VTs[64 * 32];
  __shared__ u16 Ps[4][16 * 32];
  const int tid = threadIdx.x, l = tid & 63, w = tid >> 6;
  const int qt = blockIdx.x, h = blockIdx.y, b = blockIdx.z;
  const size_t qkbase = (size_t)(b * 32 + h) * 2048;
  const size_t vbase = (size_t)(b * 16 + (h & 15)) * 2048;
  const int qrow_l = qt * 64 + w * 16 + (l & 15);
  const bf16x8 qf = *(const bf16x8*)&Q[(qkbase + qrow_l) * 32 + (l >> 4) * 8];
  f32x4 o[4] = {};
  float mrow[4] = {-1e30f, -1e30f, -1e30f, -1e30f};
  float lrow[4] = {};
  const int r0 = (l >> 4) * 4;
  const int qrow_c = qt * 64 + w * 16 + r0;
  const int nsteps = 2 * qt + 2;
  const float sc = 0.17677669529663687f;  // 1/sqrt(32)
  const f32x4 zero = {};
  for (int s = 0; s < nsteps; ++s) {
    const int kb = s * 32;
    // stage K tile [32][32] (contiguous 1024 u16)
    *(ushort4*)&Ks[tid * 4] = *(const ushort4*)&K[(qkbase + kb) * 32 + tid * 4];
    // stage V tile transposed: VTs[d][kpos]
    {
      const int kpos = tid >> 3, d0 = (tid & 7) * 8;
      const size_t vsrc = (vbase + kb + kpos) * 64 + d0;
      ushort4 va = *(const ushort4*)&V[vsrc];
      ushort4 vb = *(const ushort4*)&V[vsrc + 4];
      VTs[(d0 + 0) * 32 + kpos] = va.x;
      VTs[(d0 + 1) * 32 + kpos] = va.y;
      VTs[(d0 + 2) * 32 + kpos] = va.z;
      VTs[(d0 + 3) * 32 + kpos] = va.w;
      VTs[(d0 + 4) * 32 + kpos] = vb.x;
      VTs[(d0 + 5) * 32 + kpos] = vb.y;
      VTs[(d0 + 6) * 32 + kpos] = vb.z;
      VTs[(d0 + 7) * 32 + kpos] = vb.w;
    }
    __syncthreads();
    // QK^T: two 16-col fragments
    const bf16x8 kf0 = *(const bf16x8*)&Ks[(l & 15) * 32 + (l >> 4) * 8];
    const bf16x8 kf1 = *(const bf16x8*)&Ks[(16 + (l & 15)) * 32 + (l >> 4) * 8];
    f32x4 s0 = __builtin_amdgcn_mfma_f32_16x16x32_bf16(qf, kf0, zero, 0, 0, 0);
    f32x4 s1 = __builtin_amdgcn_mfma_f32_16x16x32_bf16(qf, kf1, zero, 0, 0, 0);
    // online softmax (per lane: 4 rows, cols kb+(l&15) and kb+16+(l&15))
#pragma unroll
    for (int r = 0; r < 4; ++r) {
      float v0 = s0[r] * sc;
      float v1 = s1[r] * sc;
      if (kb + (l & 15) > qrow_c + r) v0 = -1e30f;
      if (kb + 16 + (l & 15) > qrow_c + r) v1 = -1e30f;
      float mx = fmaxf(v0, v1);
      mx = fmaxf(mx, __shfl_xor(mx, 1, 64));
      mx = fmaxf(mx, __shfl_xor(mx, 2, 64));
      mx = fmaxf(mx, __shfl_xor(mx, 4, 64));
      mx = fmaxf(mx, __shfl_xor(mx, 8, 64));
      const float mnew = fmaxf(mrow[r], mx);
      const float sf = __expf(mrow[r] - mnew);
      mrow[r] = mnew;
      const float p0 = __expf(v0 - mnew);
      const float p1 = __expf(v1 - mnew);
      float ps = p0 + p1;
      ps += __shfl_xor(ps, 1, 64);
      ps += __shfl_xor(ps, 2, 64);
      ps += __shfl_xor(ps, 4, 64);
      ps += __shfl_xor(ps, 8, 64);
      lrow[r] = lrow[r] * sf + ps;
#pragma unroll
      for (int j = 0; j < 4; ++j) o[j][r] *= sf;
      Ps[w][(r0 + r) * 32 + (l & 15)] = f2bf(p0);
      Ps[w][(r0 + r) * 32 + 16 + (l & 15)] = f2bf(p1);
    }
    // PV: P as A-frag (own wave's LDS region), V^T as B-frags
    const bf16x8 pf = *(const bf16x8*)&Ps[w][(l & 15) * 32 + (l >> 4) * 8];
#pragma unroll
    for (int j = 0; j < 4; ++j) {
      const bf16x8 vf = *(const bf16x8*)&VTs[(j * 16 + (l & 15)) * 32 + (l >> 4) * 8];
      o[j] = __builtin_amdgcn_mfma_f32_16x16x32_bf16(pf, vf, o[j], 0, 0, 0);
    }
    __syncthreads();
  }
#pragma unroll
  for (int r = 0; r < 4; ++r) {
    const float inv = 1.0f / lrow[r];
    const size_t rowoff = (qkbase + qrow_c + r) * 64;
#pragma unroll
    for (int j = 0; j < 4; ++j) Aout[rowoff + j * 16 + (l & 15)] = o[j][r] * inv;
  }
}

// ---------------------------------------------------------------- diff + RMS
__global__ __launch_bounds__(256) void diff_rms_kernel(
    const float* __restrict__ A, const float* __restrict__ lq1,
    const float* __restrict__ lk1, const float* __restrict__ lq2,
    const float* __restrict__ lk2, u16* __restrict__ Mb) {
  const int g = threadIdx.x >> 6, d = threadIdx.x & 63;
  const int ridx = blockIdx.x * 4 + g;  // (b,h,t) flattened: 0..65535
  const int b = ridx >> 15, rem = ridx & 32767, h = rem >> 11, t = rem & 2047;
  float d1 = 0.f, d2 = 0.f;
#pragma unroll
  for (int i = 0; i < 32; ++i) {
    d1 += lq1[i] * lk1[i];
    d2 += lq2[i] * lk2[i];
  }
  const float lam = expf(d1) - expf(d2) + 0.2f;
  const float a1 = A[((size_t)(b * 32 + h) * 2048 + t) * 64 + d];
  const float a2 = A[((size_t)(b * 32 + 16 + h) * 2048 + t) * 64 + d];
  const float df = a1 - lam * a2;
  float ss = df * df;
  ss += __shfl_xor(ss, 1, 64);
  ss += __shfl_xor(ss, 2, 64);
  ss += __shfl_xor(ss, 4, 64);
  ss += __shfl_xor(ss, 8, 64);
  ss += __shfl_xor(ss, 16, 64);
  ss += __shfl_xor(ss, 32, 64);
  const float rms = rsqrtf(ss * (1.0f / 64.0f) + 1e-5f);
  Mb[((size_t)(b * 2048 + t)) * 1024 + h * 64 + d] = f2bf(0.8f * df * rms);
}

// ---------------------------------------------------------------- launch
extern "C" void kernel_launch(void* const* d_in, const int* in_sizes, int n_in,
                              void* d_out, int out_size, void* d_ws, size_t ws_size,
                              hipStream_t stream) {
  const float* x = (const float*)d_in[0];
  const float* Wa = (const float*)d_in[1];
  const float* Wp = (const float*)d_in[2];
  const float* lq1 = (const float*)d_in[3];
  const float* lk1 = (const float*)d_in[4];
  const float* lq2 = (const float*)d_in[5];
  const float* lk2 = (const float*)d_in[6];
  if (ws_size < (size_t)(64u << 20)) return;  // need 64 MiB scratch

  char* ws = (char*)d_ws;
  u16* Qarr = (u16*)(ws);                                // 8 MiB
  u16* Karr = (u16*)(ws + (8u << 20));                   // 8 MiB
  u16* Varr = (u16*)(ws + (16u << 20));                  // 8 MiB
  u16* WpT = (u16*)(ws + (24u << 20));                   // 2 MiB
  char* arena = ws + (26u << 20);                        // 38 MiB arena
  u16* xb = (u16*)(arena);                               // 8 MiB  (dead after gemm1)
  u16* WaT = (u16*)(arena + 8388608);                    // 6 MiB  (dead after gemm1)
  u16* qkvb = (u16*)(arena + 8388608 + 6291456);         // 24 MiB (dead after rope)
  float* Aout = (float*)(arena);                         // 32 MiB (overlays xb/WaT/qkvb)
  u16* Mbuf = Qarr;                                      // 8 MiB  (overlays Q after attn)

  cvt_f32_bf16<<<4096, 256, 0, stream>>>(x, xb, 1048576);
  transpose_f32_to_bf16<<<dim3(96, 32), 256, 0, stream>>>(Wa, WaT, 1024, 3072);
  transpose_f32_to_bf16<<<dim3(32, 32), 256, 0, stream>>>(Wp, WpT, 1024, 1024);
  gemm_bf16_kernel<true><<<dim3(24, 32), 256, 0, stream>>>(xb, WaT, qkvb, 4096, 3072, 1024);
  rope_kernel<<<4096, 256, 0, stream>>>(qkvb, Qarr, Karr, Varr);
  attn_kernel<<<dim3(32, 32, 2), 256, 0, stream>>>(Qarr, Karr, Varr, Aout);
  diff_rms_kernel<<<16384, 256, 0, stream>>>(Aout, lq1, lk1, lq2, lk2, Mbuf);
  gemm_bf16_kernel<false><<<dim3(8, 32), 256, 0, stream>>>(Mbuf, WpT, d_out, 4096, 1024, 1024);
}

// Round 2
// 214.592 us; speedup vs baseline: 2.2629x; 2.2629x over previous
//
#include <hip/hip_runtime.h>

// MultiHeadDiffAttention: B=2, T=2048, C=1024, H=16 (v-heads), 2H=32 (q/k heads),
// D=32, Dv=64. cvt -> transpose weights -> qkv GEMM (global_load_lds MFMA) ->
// RoPE -> V-transpose -> balanced flash attention (KVBLK=64, paired q-tiles) ->
// diff+RMS -> out GEMM.

typedef unsigned short u16;
typedef __bf16 bf16x8 __attribute__((ext_vector_type(8)));
typedef float f32x4 __attribute__((ext_vector_type(4)));

__device__ __forceinline__ u16 f2bf(float f) {
  return __builtin_bit_cast(u16, (__bf16)f);
}
__device__ __forceinline__ float bf2f(u16 u) {
  return (float)__builtin_bit_cast(__bf16, u);
}

// async global->LDS, 16B per lane. LDS dest must be wave-uniform-base + lane*16.
__device__ __forceinline__ void gload16(const u16* g, u16* l) {
  __builtin_amdgcn_global_load_lds(
      (const __attribute__((address_space(1))) unsigned int*)g,
      (__attribute__((address_space(3))) unsigned int*)l, 16, 0, 0);
}

// ---------------------------------------------------------------- cvt x->bf16
__global__ __launch_bounds__(256) void cvt_f32_bf16(const float* __restrict__ in,
                                                    u16* __restrict__ out, int n4) {
  int i = blockIdx.x * 256 + threadIdx.x;
  if (i < n4) {
    float4 v = ((const float4*)in)[i];
    ushort4 o;
    o.x = f2bf(v.x); o.y = f2bf(v.y); o.z = f2bf(v.z); o.w = f2bf(v.w);
    ((ushort4*)out)[i] = o;
  }
}

// ------------------------------------------- transpose fp32 [R][Cn] -> bf16 [Cn][R]
__global__ __launch_bounds__(256) void transpose_f32_to_bf16(
    const float* __restrict__ in, u16* __restrict__ out, int R, int Cn) {
  __shared__ float tile[32][33];
  const int tx = threadIdx.x & 31, ty = threadIdx.x >> 5;  // ty 0..7
  const int c0 = blockIdx.x * 32, r0 = blockIdx.y * 32;
#pragma unroll
  for (int rr = 0; rr < 4; ++rr)
    tile[ty + rr * 8][tx] = in[(size_t)(r0 + ty + rr * 8) * Cn + c0 + tx];
  __syncthreads();
#pragma unroll
  for (int rr = 0; rr < 4; ++rr)
    out[(size_t)(c0 + ty + rr * 8) * R + r0 + tx] = f2bf(tile[tx][ty + rr * 8]);
}

// ---------------------------------------------------------------- bf16 GEMM (m97 style)
// A: [M][K] bf16 row-major; BT: [N][K] bf16; C: [M][N]. 128x128 tile, BK=32.
template <bool OUT_BF16>
__global__ __launch_bounds__(256) void gemm_bf16_kernel(
    const u16* __restrict__ A, const u16* __restrict__ BT, void* __restrict__ Cout,
    int Mdim, int Ndim, int Kdim) {
  __shared__ u16 As[128 * 32];
  __shared__ u16 Bs[128 * 32];
  const int tid = threadIdx.x;
  const int l = tid & 63;
  const int w = tid >> 6;
  const int bm = blockIdx.y, bn = blockIdx.x;
  const int wm = w >> 1, wn = w & 1;
  const int rowA0 = bm * 128, rowB0 = bn * 128;
  const int r_ = tid >> 2;        // 0..63
  const int s_ = (tid & 3) * 8;   // k element offset
  const u16* Ag = &A[(size_t)(rowA0 + r_) * Kdim + s_];
  const u16* Bg = &BT[(size_t)(rowB0 + r_) * Kdim + s_];
  const size_t rstride = (size_t)64 * Kdim;
  f32x4 acc[4][4] = {};
  for (int k0 = 0; k0 < Kdim; k0 += 32) {
    gload16(Ag + k0, &As[r_ * 32 + s_]);
    gload16(Ag + rstride + k0, &As[2048 + r_ * 32 + s_]);
    gload16(Bg + k0, &Bs[r_ * 32 + s_]);
    gload16(Bg + rstride + k0, &Bs[2048 + r_ * 32 + s_]);
    __syncthreads();
    bf16x8 a[4], b[4];
#pragma unroll
    for (int i = 0; i < 4; ++i)
      a[i] = *(const bf16x8*)&As[(wm * 64 + i * 16 + (l & 15)) * 32 + (l >> 4) * 8];
#pragma unroll
    for (int j = 0; j < 4; ++j)
      b[j] = *(const bf16x8*)&Bs[(wn * 64 + j * 16 + (l & 15)) * 32 + (l >> 4) * 8];
#pragma unroll
    for (int i = 0; i < 4; ++i)
#pragma unroll
      for (int j = 0; j < 4; ++j)
        acc[i][j] = __builtin_amdgcn_mfma_f32_16x16x32_bf16(a[i], b[j], acc[i][j], 0, 0, 0);
    __syncthreads();
  }
  const int cr = (l >> 4) * 4;
  const int cc = l & 15;
#pragma unroll
  for (int i = 0; i < 4; ++i)
#pragma unroll
    for (int j = 0; j < 4; ++j)
#pragma unroll
      for (int r = 0; r < 4; ++r) {
        const int row = rowA0 + wm * 64 + i * 16 + cr + r;
        const int col = rowB0 + wn * 64 + j * 16 + cc;
        if (OUT_BF16)
          ((u16*)Cout)[(size_t)row * Ndim + col] = f2bf(acc[i][j][r]);
        else
          ((float*)Cout)[(size_t)row * Ndim + col] = acc[i][j][r];
      }
}

// ---------------------------------------------------------------- RoPE (q,k only)
// qkv bf16 [4096][3072] -> Q,K bf16 (B,32,T,32) roped. One block per (b,t) row.
__global__ __launch_bounds__(256) void rope_kernel(const u16* __restrict__ qkv,
                                                   u16* __restrict__ Q,
                                                   u16* __restrict__ K) {
  const int row = blockIdx.x;  // 0..4095
  const int b = row >> 11, t = row & 2047;
  const int tid = threadIdx.x;
  const int isK = tid >> 7, hh = (tid >> 2) & 31, i4 = tid & 3;
  union { uint4 v; u16 s[8]; } in_, out_;
  in_.v = *(const uint4*)&qkv[(size_t)row * 3072 + isK * 1024 + hh * 32 + i4 * 8];
#pragma unroll
  for (int jj = 0; jj < 4; ++jj) {
    const int i = i4 * 4 + jj;
    const float x1 = bf2f(in_.s[2 * jj]), x2 = bf2f(in_.s[2 * jj + 1]);
    const float theta = exp2f(-0.83048202372184059f * (float)i);  // 10000^(-i/16)
    float sn, cs;
    sincosf((float)t * theta, &sn, &cs);
    out_.s[2 * jj] = f2bf(x1 * cs - x2 * sn);
    out_.s[2 * jj + 1] = f2bf(x1 * sn + x2 * cs);
  }
  u16* dst = isK ? K : Q;
  *(uint4*)&dst[((size_t)(b * 32 + hh) * 2048 + t) * 32 + i4 * 8] = out_.v;
}

// -------------------------------------- V transpose: qkv v-part -> VT (B,16,64,T)
__global__ __launch_bounds__(256) void vtrans_kernel(const u16* __restrict__ qkv,
                                                     u16* __restrict__ VT) {
  __shared__ u16 tile[32][33];
  const int tx = threadIdx.x & 31, ty = threadIdx.x >> 5;
  const int t0 = blockIdx.x * 32, d0 = blockIdx.y * 32, bh = blockIdx.z;
  const int b = bh >> 4, hv = bh & 15;
#pragma unroll
  for (int k = 0; k < 4; ++k)
    tile[ty + 8 * k][tx] =
        qkv[(size_t)(b * 2048 + t0 + ty + 8 * k) * 3072 + 2048 + hv * 64 + d0 + tx];
  __syncthreads();
#pragma unroll
  for (int k = 0; k < 4; ++k)
    VT[((size_t)bh * 64 + d0 + ty + 8 * k) * 2048 + t0 + tx] = tile[tx][ty + 8 * k];
}

// ---------------------------------------------------------------- flash attention
// grid (8 pairs, 32 heads, B). 512 thr = 8 waves; block handles q-tiles p and 15-p
// (128 rows each, 16/wave). KVBLK=64. Total steps/block = 34 (perfectly balanced).
__global__ __launch_bounds__(512, 4) void attn_kernel(const u16* __restrict__ Q,
                                                      const u16* __restrict__ K,
                                                      const u16* __restrict__ VT,
                                                      u16* __restrict__ Aout) {
  __shared__ u16 Ks[64 * 40];     // K tile [64 kpos][32 d], row stride 40 u16
  __shared__ u16 Vs[64 * 72];     // V^T tile [64 d][64 kpos], row stride 72 u16
  __shared__ u16 Ps[8 * 16 * 72]; // per-wave P [16 q][64 k], row stride 72 u16
  const int tid = threadIdx.x, l = tid & 63, w = tid >> 6;
  const int pp = blockIdx.x, h = blockIdx.y, b = blockIdx.z;
  const size_t qkbase = (size_t)(b * 32 + h) * 2048;
  const size_t vtb = (size_t)(b * 16 + (h & 15)) * 64;
  const int li = l & 15, lh = l >> 4;
  const int r0 = lh * 4;
  u16* Pw = &Ps[w * 16 * 72];
  const float sc = 0.17677669529663687f;  // 1/sqrt(32)
  const f32x4 zero = {};
  const int st_row = (tid & 255) >> 2;
  const int st_slot = tid & 3;

  for (int half = 0; half < 2; ++half) {
    const int qt = half ? (15 - pp) : pp;
    const int q0 = qt * 128;
    const int qw = q0 + w * 16;
    const bf16x8 qf = *(const bf16x8*)&Q[(qkbase + qw + li) * 32 + lh * 8];
    f32x4 o[4] = {};
    float mrow[4] = {-1e30f, -1e30f, -1e30f, -1e30f};
    float lsum[4] = {};
    const int nsteps = 2 * qt + 2;
    for (int s = 0; s < nsteps; ++s) {
      const int kb = s * 64;
      if (tid < 256) {  // stage K tile: 256 slots of 16B, coalesced
        *(uint4*)&Ks[st_row * 40 + st_slot * 8] =
            *(const uint4*)&K[(qkbase + kb + st_row) * 32 + st_slot * 8];
      } else {          // stage V^T tile: 512 slots, 2 per thread
        const u16* src = &VT[(vtb + st_row) * 2048 + kb];
        *(uint4*)&Vs[st_row * 72 + st_slot * 8] = *(const uint4*)&src[st_slot * 8];
        *(uint4*)&Vs[st_row * 72 + (st_slot + 4) * 8] =
            *(const uint4*)&src[(st_slot + 4) * 8];
      }
      __syncthreads();
      if (qw + 15 >= kb) {  // wave-uniform: skip fully-masked waves
        f32x4 sj[4];
#pragma unroll
        for (int jj = 0; jj < 4; ++jj) {
          const bf16x8 kf = *(const bf16x8*)&Ks[(jj * 16 + li) * 40 + lh * 8];
          sj[jj] = __builtin_amdgcn_mfma_f32_16x16x32_bf16(qf, kf, zero, 0, 0, 0);
        }
        const bool need_mask = (kb + 63 > qw);
#pragma unroll
        for (int r = 0; r < 4; ++r) {
          const int q = qw + r0 + r;
          float v0 = sj[0][r] * sc, v1 = sj[1][r] * sc;
          float v2 = sj[2][r] * sc, v3 = sj[3][r] * sc;
          if (need_mask) {
            if (kb + li > q) v0 = -1e30f;
            if (kb + 16 + li > q) v1 = -1e30f;
            if (kb + 32 + li > q) v2 = -1e30f;
            if (kb + 48 + li > q) v3 = -1e30f;
          }
          float mx = fmaxf(fmaxf(v0, v1), fmaxf(v2, v3));
          mx = fmaxf(mx, __shfl_xor(mx, 1, 64));
          mx = fmaxf(mx, __shfl_xor(mx, 2, 64));
          mx = fmaxf(mx, __shfl_xor(mx, 4, 64));
          mx = fmaxf(mx, __shfl_xor(mx, 8, 64));
          const float mnew = fmaxf(mrow[r], mx);
          const float sf = __expf(mrow[r] - mnew);
          mrow[r] = mnew;
          const float p0 = __expf(v0 - mnew), p1 = __expf(v1 - mnew);
          const float p2 = __expf(v2 - mnew), p3 = __expf(v3 - mnew);
          float ps = (p0 + p1) + (p2 + p3);
          ps += __shfl_xor(ps, 1, 64);
          ps += __shfl_xor(ps, 2, 64);
          ps += __shfl_xor(ps, 4, 64);
          ps += __shfl_xor(ps, 8, 64);
          lsum[r] = lsum[r] * sf + ps;
          o[0][r] *= sf; o[1][r] *= sf; o[2][r] *= sf; o[3][r] *= sf;
          const int prow = (r0 + r) * 72;
          Pw[prow + li] = f2bf(p0);
          Pw[prow + 16 + li] = f2bf(p1);
          Pw[prow + 32 + li] = f2bf(p2);
          Pw[prow + 48 + li] = f2bf(p3);
        }
        const bf16x8 pa0 = *(const bf16x8*)&Pw[li * 72 + lh * 8];
        const bf16x8 pa1 = *(const bf16x8*)&Pw[li * 72 + 32 + lh * 8];
#pragma unroll
        for (int jj = 0; jj < 4; ++jj) {
          const bf16x8 vf0 = *(const bf16x8*)&Vs[(jj * 16 + li) * 72 + lh * 8];
          const bf16x8 vf1 = *(const bf16x8*)&Vs[(jj * 16 + li) * 72 + 32 + lh * 8];
          o[jj] = __builtin_amdgcn_mfma_f32_16x16x32_bf16(pa0, vf0, o[jj], 0, 0, 0);
          o[jj] = __builtin_amdgcn_mfma_f32_16x16x32_bf16(pa1, vf1, o[jj], 0, 0, 0);
        }
      }
      __syncthreads();
    }
#pragma unroll
    for (int r = 0; r < 4; ++r) {
      const float inv = 1.0f / lsum[r];
      const size_t rowoff = (qkbase + qw + r0 + r) * 64;
#pragma unroll
      for (int jj = 0; jj < 4; ++jj)
        Aout[rowoff + jj * 16 + li] = f2bf(o[jj][r] * inv);
    }
  }
}

// ---------------------------------------------------------------- diff + RMS
__global__ __launch_bounds__(256) void diff_rms_kernel(
    const u16* __restrict__ A, const float* __restrict__ lq1,
    const float* __restrict__ lk1, const float* __restrict__ lq2,
    const float* __restrict__ lk2, u16* __restrict__ Mb) {
  const int g = threadIdx.x >> 5;          // 0..7 (row within block)
  const int dl = (threadIdx.x & 31) * 2;   // d offset
  const int ridx = blockIdx.x * 8 + g;     // (b,h,t): 0..65535
  const int b = ridx >> 15, rem = ridx & 32767, h = rem >> 11, t = rem & 2047;
  float d1 = 0.f, d2 = 0.f;
#pragma unroll
  for (int i = 0; i < 32; ++i) {
    d1 += lq1[i] * lk1[i];
    d2 += lq2[i] * lk2[i];
  }
  const float lam = expf(d1) - expf(d2) + 0.2f;
  const size_t base1 = ((size_t)(b * 32 + h) * 2048 + t) * 64 + dl;
  const size_t base2 = ((size_t)(b * 32 + 16 + h) * 2048 + t) * 64 + dl;
  const ushort2 a1 = *(const ushort2*)&A[base1];
  const ushort2 a2 = *(const ushort2*)&A[base2];
  const float df0 = bf2f(a1.x) - lam * bf2f(a2.x);
  const float df1 = bf2f(a1.y) - lam * bf2f(a2.y);
  float ss = df0 * df0 + df1 * df1;
  ss += __shfl_xor(ss, 1, 64);
  ss += __shfl_xor(ss, 2, 64);
  ss += __shfl_xor(ss, 4, 64);
  ss += __shfl_xor(ss, 8, 64);
  ss += __shfl_xor(ss, 16, 64);
  const float rms = rsqrtf(ss * (1.0f / 64.0f) + 1e-5f);
  ushort2 o;
  o.x = f2bf(0.8f * df0 * rms);
  o.y = f2bf(0.8f * df1 * rms);
  *(ushort2*)&Mb[((size_t)(b * 2048 + t)) * 1024 + h * 64 + dl] = o;
}

// ---------------------------------------------------------------- launch
extern "C" void kernel_launch(void* const* d_in, const int* in_sizes, int n_in,
                              void* d_out, int out_size, void* d_ws, size_t ws_size,
                              hipStream_t stream) {
  const float* x = (const float*)d_in[0];
  const float* Wa = (const float*)d_in[1];
  const float* Wp = (const float*)d_in[2];
  const float* lq1 = (const float*)d_in[3];
  const float* lk1 = (const float*)d_in[4];
  const float* lq2 = (const float*)d_in[5];
  const float* lk2 = (const float*)d_in[6];
  if (ws_size < (size_t)(64u << 20)) return;  // need 64 MiB scratch

  char* ws = (char*)d_ws;
  u16* Qarr = (u16*)(ws);                        // 8 MiB
  u16* Karr = (u16*)(ws + (8u << 20));           // 8 MiB
  u16* VTarr = (u16*)(ws + (16u << 20));         // 8 MiB
  u16* WpT = (u16*)(ws + (24u << 20));           // 2 MiB
  char* arena = ws + (26u << 20);                // 38 MiB arena
  u16* xb = (u16*)(arena);                       // 8 MiB  (dead after gemm1)
  u16* WaT = (u16*)(arena + (8u << 20));         // 6 MiB  (dead after gemm1)
  u16* qkvb = (u16*)(arena + (14u << 20));       // 24 MiB (dead after vtrans)
  u16* Aout = (u16*)(arena);                     // 16 MiB bf16 (overlays xb/WaT/qkvb-head)
  u16* Mbuf = Qarr;                              // 8 MiB  (overlays Q after attn)

  cvt_f32_bf16<<<4096, 256, 0, stream>>>(x, xb, 1048576);
  transpose_f32_to_bf16<<<dim3(96, 32), 256, 0, stream>>>(Wa, WaT, 1024, 3072);
  transpose_f32_to_bf16<<<dim3(32, 32), 256, 0, stream>>>(Wp, WpT, 1024, 1024);
  gemm_bf16_kernel<true><<<dim3(24, 32), 256, 0, stream>>>(xb, WaT, qkvb, 4096, 3072, 1024);
  rope_kernel<<<4096, 256, 0, stream>>>(qkvb, Qarr, Karr);
  vtrans_kernel<<<dim3(64, 2, 32), 256, 0, stream>>>(qkvb, VTarr);
  attn_kernel<<<dim3(8, 32, 2), 512, 0, stream>>>(Qarr, Karr, VTarr, Aout);
  diff_rms_kernel<<<8192, 256, 0, stream>>>(Aout, lq1, lk1, lq2, lk2, Mbuf);
  gemm_bf16_kernel<false><<<dim3(8, 32), 256, 0, stream>>>(Mbuf, WpT, d_out, 4096, 1024, 1024);
}

// Round 3
// 185.794 us; speedup vs baseline: 2.6137x; 1.1550x over previous
//
#include <hip/hip_runtime.h>

// MultiHeadDiffAttention: B=2, T=2048, C=1024, H=16 (v-heads), 2H=32 (q/k heads),
// D=32, Dv=64. cvt -> transpose weights -> qkv GEMM (global_load_lds MFMA) ->
// RoPE -> V-transpose -> swapped-QK^T 32x32 flash attention -> diff+RMS -> out GEMM.

typedef unsigned short u16;
typedef __bf16 bf16x8 __attribute__((ext_vector_type(8)));
typedef float f32x4 __attribute__((ext_vector_type(4)));
typedef float f32x16 __attribute__((ext_vector_type(16)));

__device__ __forceinline__ u16 f2bf(float f) {
  return __builtin_bit_cast(u16, (__bf16)f);
}
__device__ __forceinline__ float bf2f(u16 u) {
  return (float)__builtin_bit_cast(__bf16, u);
}
__device__ __forceinline__ unsigned pk2(float a, float b) {
  return (unsigned)f2bf(a) | ((unsigned)f2bf(b) << 16);
}

// async global->LDS, 16B per lane. LDS dest must be wave-uniform-base + lane*16.
__device__ __forceinline__ void gload16(const u16* g, u16* l) {
  __builtin_amdgcn_global_load_lds(
      (const __attribute__((address_space(1))) unsigned int*)g,
      (__attribute__((address_space(3))) unsigned int*)l, 16, 0, 0);
}

// ---------------------------------------------------------------- cvt x->bf16
__global__ __launch_bounds__(256) void cvt_f32_bf16(const float* __restrict__ in,
                                                    u16* __restrict__ out, int n4) {
  int i = blockIdx.x * 256 + threadIdx.x;
  if (i < n4) {
    float4 v = ((const float4*)in)[i];
    ushort4 o;
    o.x = f2bf(v.x); o.y = f2bf(v.y); o.z = f2bf(v.z); o.w = f2bf(v.w);
    ((ushort4*)out)[i] = o;
  }
}

// ------------------------------------------- transpose fp32 [R][Cn] -> bf16 [Cn][R]
__global__ __launch_bounds__(256) void transpose_f32_to_bf16(
    const float* __restrict__ in, u16* __restrict__ out, int R, int Cn) {
  __shared__ float tile[32][33];
  const int tx = threadIdx.x & 31, ty = threadIdx.x >> 5;  // ty 0..7
  const int c0 = blockIdx.x * 32, r0 = blockIdx.y * 32;
#pragma unroll
  for (int rr = 0; rr < 4; ++rr)
    tile[ty + rr * 8][tx] = in[(size_t)(r0 + ty + rr * 8) * Cn + c0 + tx];
  __syncthreads();
#pragma unroll
  for (int rr = 0; rr < 4; ++rr)
    out[(size_t)(c0 + ty + rr * 8) * R + r0 + tx] = f2bf(tile[tx][ty + rr * 8]);
}

// ---------------------------------------------------------------- bf16 GEMM (m97 style)
// A: [M][K] bf16 row-major; BT: [N][K] bf16; C: [M][N]. 128x128 tile, BK=32.
template <bool OUT_BF16>
__global__ __launch_bounds__(256) void gemm_bf16_kernel(
    const u16* __restrict__ A, const u16* __restrict__ BT, void* __restrict__ Cout,
    int Mdim, int Ndim, int Kdim) {
  __shared__ u16 As[128 * 32];
  __shared__ u16 Bs[128 * 32];
  const int tid = threadIdx.x;
  const int l = tid & 63;
  const int w = tid >> 6;
  const int bm = blockIdx.y, bn = blockIdx.x;
  const int wm = w >> 1, wn = w & 1;
  const int rowA0 = bm * 128, rowB0 = bn * 128;
  const int r_ = tid >> 2;        // 0..63
  const int s_ = (tid & 3) * 8;   // k element offset
  const u16* Ag = &A[(size_t)(rowA0 + r_) * Kdim + s_];
  const u16* Bg = &BT[(size_t)(rowB0 + r_) * Kdim + s_];
  const size_t rstride = (size_t)64 * Kdim;
  f32x4 acc[4][4] = {};
  for (int k0 = 0; k0 < Kdim; k0 += 32) {
    gload16(Ag + k0, &As[r_ * 32 + s_]);
    gload16(Ag + rstride + k0, &As[2048 + r_ * 32 + s_]);
    gload16(Bg + k0, &Bs[r_ * 32 + s_]);
    gload16(Bg + rstride + k0, &Bs[2048 + r_ * 32 + s_]);
    __syncthreads();
    bf16x8 a[4], b[4];
#pragma unroll
    for (int i = 0; i < 4; ++i)
      a[i] = *(const bf16x8*)&As[(wm * 64 + i * 16 + (l & 15)) * 32 + (l >> 4) * 8];
#pragma unroll
    for (int j = 0; j < 4; ++j)
      b[j] = *(const bf16x8*)&Bs[(wn * 64 + j * 16 + (l & 15)) * 32 + (l >> 4) * 8];
#pragma unroll
    for (int i = 0; i < 4; ++i)
#pragma unroll
      for (int j = 0; j < 4; ++j)
        acc[i][j] = __builtin_amdgcn_mfma_f32_16x16x32_bf16(a[i], b[j], acc[i][j], 0, 0, 0);
    __syncthreads();
  }
  const int cr = (l >> 4) * 4;
  const int cc = l & 15;
#pragma unroll
  for (int i = 0; i < 4; ++i)
#pragma unroll
    for (int j = 0; j < 4; ++j)
#pragma unroll
      for (int r = 0; r < 4; ++r) {
        const int row = rowA0 + wm * 64 + i * 16 + cr + r;
        const int col = rowB0 + wn * 64 + j * 16 + cc;
        if (OUT_BF16)
          ((u16*)Cout)[(size_t)row * Ndim + col] = f2bf(acc[i][j][r]);
        else
          ((float*)Cout)[(size_t)row * Ndim + col] = acc[i][j][r];
      }
}

// ---------------------------------------------------------------- RoPE (q,k only)
__global__ __launch_bounds__(256) void rope_kernel(const u16* __restrict__ qkv,
                                                   u16* __restrict__ Q,
                                                   u16* __restrict__ K) {
  const int row = blockIdx.x;  // 0..4095
  const int b = row >> 11, t = row & 2047;
  const int tid = threadIdx.x;
  const int isK = tid >> 7, hh = (tid >> 2) & 31, i4 = tid & 3;
  union { uint4 v; u16 s[8]; } in_, out_;
  in_.v = *(const uint4*)&qkv[(size_t)row * 3072 + isK * 1024 + hh * 32 + i4 * 8];
#pragma unroll
  for (int jj = 0; jj < 4; ++jj) {
    const int i = i4 * 4 + jj;
    const float x1 = bf2f(in_.s[2 * jj]), x2 = bf2f(in_.s[2 * jj + 1]);
    const float theta = exp2f(-0.83048202372184059f * (float)i);  // 10000^(-i/16)
    float sn, cs;
    sincosf((float)t * theta, &sn, &cs);
    out_.s[2 * jj] = f2bf(x1 * cs - x2 * sn);
    out_.s[2 * jj + 1] = f2bf(x1 * sn + x2 * cs);
  }
  u16* dst = isK ? K : Q;
  *(uint4*)&dst[((size_t)(b * 32 + hh) * 2048 + t) * 32 + i4 * 8] = out_.v;
}

// -------------------------------------- V transpose: qkv v-part -> VT (B,16,64,T)
__global__ __launch_bounds__(256) void vtrans_kernel(const u16* __restrict__ qkv,
                                                     u16* __restrict__ VT) {
  __shared__ u16 tile[32][33];
  const int tx = threadIdx.x & 31, ty = threadIdx.x >> 5;
  const int t0 = blockIdx.x * 32, d0 = blockIdx.y * 32, bh = blockIdx.z;
  const int b = bh >> 4, hv = bh & 15;
#pragma unroll
  for (int k = 0; k < 4; ++k)
    tile[ty + 8 * k][tx] =
        qkv[(size_t)(b * 2048 + t0 + ty + 8 * k) * 3072 + 2048 + hv * 64 + d0 + tx];
  __syncthreads();
#pragma unroll
  for (int k = 0; k < 4; ++k)
    VT[((size_t)bh * 64 + d0 + ty + 8 * k) * 2048 + t0 + tx] = tile[tx][ty + 8 * k];
}

// ---------------------------------------------------------------- flash attention
// Swapped QK^T with 32x32x16 MFMA: S^T = K·Q^T so each lane owns one q-row's
// scores (col=lane&31=q). 4 waves x 32 q = 128 q-rows/block; tile pairs (p,15-p)
// -> 34 KV steps/block, perfectly balanced. Grid (8,32,2) = 512 blocks, 2/CU.
__global__ __launch_bounds__(256, 2) void attn_kernel(const u16* __restrict__ Q,
                                                      const u16* __restrict__ K,
                                                      const u16* __restrict__ VT,
                                                      u16* __restrict__ Aout) {
  __shared__ u16 Ks[64 * 34];       // [k=64][d=32], stride 34 (17-bank step)
  __shared__ u16 Vs[64 * 66];       // [dv=64][k=64], stride 66 (33-bank step)
  __shared__ u16 Os[4 * 32 * 66];   // per-wave O staging [32 q][64 dv], stride 66
  const int tid = threadIdx.x, l = tid & 63, w = tid >> 6;
  const int pp = blockIdx.x, h = blockIdx.y, b = blockIdx.z;
  const size_t qkbase = (size_t)(b * 32 + h) * 2048;
  const size_t vtb = (size_t)(b * 16 + (h & 15)) * 64;
  const int lq = l & 31, hi = l >> 5;
  const float sc = 0.17677669529663687f;  // 1/sqrt(32)
  const f32x16 z16 = {};
  // staging indices
  const int krow = tid >> 2, ksl = (tid & 3) * 8;   // K tile: 1 uint4/thread
  const int dva = tid >> 3, vsl = (tid & 7) * 8;    // V tile: 2 uint4/thread
  const int dvb = dva + 32;

  for (int half = 0; half < 2; ++half) {
    const int qt = half ? (15 - pp) : pp;
    const int q0 = qt * 128;
    const int qw = q0 + w * 32;
    const int q = qw + lq;
    const bf16x8 qf0 = *(const bf16x8*)&Q[(qkbase + q) * 32 + hi * 8];
    const bf16x8 qf1 = *(const bf16x8*)&Q[(qkbase + q) * 32 + 16 + hi * 8];
    f32x16 olo = {}, ohi = {};
    float mrow = -1e30f, lsum = 0.f;
    const int nsteps = 2 * qt + 2;
    for (int s = 0; s < nsteps; ++s) {
      const int kb = s * 64;
      *(uint4*)&Ks[krow * 34 + ksl] =
          *(const uint4*)&K[(qkbase + kb + krow) * 32 + ksl];
      *(uint4*)&Vs[dva * 66 + vsl] =
          *(const uint4*)&VT[(vtb + dva) * 2048 + kb + vsl];
      *(uint4*)&Vs[dvb * 66 + vsl] =
          *(const uint4*)&VT[(vtb + dvb) * 2048 + kb + vsl];
      __syncthreads();
      if (qw + 31 >= kb) {  // wave-uniform skip of fully-masked waves
        // S^T[k][q] = K·Q^T  (2 k-tiles x 2 d-halves)
        f32x16 s0_, s1_;
        {
          const bf16x8 ka0 = *(const bf16x8*)&Ks[lq * 34 + hi * 8];
          const bf16x8 ka1 = *(const bf16x8*)&Ks[lq * 34 + 16 + hi * 8];
          s0_ = __builtin_amdgcn_mfma_f32_32x32x16_bf16(ka0, qf0, z16, 0, 0, 0);
          s0_ = __builtin_amdgcn_mfma_f32_32x32x16_bf16(ka1, qf1, s0_, 0, 0, 0);
          const bf16x8 kc0 = *(const bf16x8*)&Ks[(32 + lq) * 34 + hi * 8];
          const bf16x8 kc1 = *(const bf16x8*)&Ks[(32 + lq) * 34 + 16 + hi * 8];
          s1_ = __builtin_amdgcn_mfma_f32_32x32x16_bf16(kc0, qf0, z16, 0, 0, 0);
          s1_ = __builtin_amdgcn_mfma_f32_32x32x16_bf16(kc1, qf1, s1_, 0, 0, 0);
        }
        // scale + causal mask; k(reg) = (r&3)+8*(r>>2)+4*hi
        const bool nm = (kb + 63 > qw);
        float t16[16];
#pragma unroll
        for (int r = 0; r < 16; ++r) {
          const int kr = (r & 3) + 8 * (r >> 2) + 4 * hi;
          float v0 = s0_[r] * sc, v1 = s1_[r] * sc;
          if (nm) {
            if (kb + kr > q) v0 = -1e30f;
            if (kb + 32 + kr > q) v1 = -1e30f;
          }
          s0_[r] = v0; s1_[r] = v1;
          t16[r] = fmaxf(v0, v1);
        }
#pragma unroll
        for (int d = 8; d >= 1; d >>= 1)
#pragma unroll
          for (int r = 0; r < d; ++r) t16[r] = fmaxf(t16[r], t16[r + d]);
        const float vmax = fmaxf(t16[0], __shfl_xor(t16[0], 32, 64));
        const float mnew = fmaxf(mrow, vmax);
        const float sf = __expf(mrow - mnew);
        mrow = mnew;
        float a16[16];
#pragma unroll
        for (int r = 0; r < 16; ++r) {
          const float p0 = __expf(s0_[r] - mnew);
          const float p1 = __expf(s1_[r] - mnew);
          s0_[r] = p0; s1_[r] = p1;
          a16[r] = p0 + p1;
        }
#pragma unroll
        for (int d = 8; d >= 1; d >>= 1)
#pragma unroll
          for (int r = 0; r < d; ++r) a16[r] += a16[r + d];
        const float psum = a16[0] + __shfl_xor(a16[0], 32, 64);
        lsum = lsum * sf + psum;
#pragma unroll
        for (int r = 0; r < 16; ++r) { olo[r] *= sf; ohi[r] *= sf; }
        // pack P -> bf16; half-exchange to form P^T B-fragments
        unsigned pw[16];
#pragma unroll
        for (int j = 0; j < 8; ++j) {
          pw[j] = pk2(s0_[2 * j], s0_[2 * j + 1]);
          pw[8 + j] = pk2(s1_[2 * j], s1_[2 * j + 1]);
        }
        bf16x8 pa[4];
#pragma unroll
        for (int t2 = 0; t2 < 2; ++t2)
#pragma unroll
          for (int sl2 = 0; sl2 < 2; ++sl2) {
            const unsigned* wt = &pw[t2 * 8 + sl2 * 4];
            const unsigned ua = hi ? wt[0] : wt[2];
            const unsigned ub = hi ? wt[1] : wt[3];
            const unsigned sa = __shfl_xor(ua, 32, 64);
            const unsigned sb = __shfl_xor(ub, 32, 64);
            union { unsigned u[4]; bf16x8 v; } fr;
            fr.u[0] = hi ? sa : wt[0];
            fr.u[1] = hi ? sb : wt[1];
            fr.u[2] = hi ? wt[2] : sa;
            fr.u[3] = hi ? wt[3] : sb;
            pa[t2 * 2 + sl2] = fr.v;
          }
        // O^T += V^T · P^T  (4 k-slices x 2 dv-halves)
#pragma unroll
        for (int ks = 0; ks < 4; ++ks) {
          const bf16x8 va = *(const bf16x8*)&Vs[lq * 66 + ks * 16 + hi * 8];
          const bf16x8 vb = *(const bf16x8*)&Vs[(32 + lq) * 66 + ks * 16 + hi * 8];
          olo = __builtin_amdgcn_mfma_f32_32x32x16_bf16(va, pa[ks], olo, 0, 0, 0);
          ohi = __builtin_amdgcn_mfma_f32_32x32x16_bf16(vb, pa[ks], ohi, 0, 0, 0);
        }
      }
      __syncthreads();
    }
    // epilogue: normalize, stage in LDS, coalesced write
    const float inv = 1.0f / lsum;
    u16* Ow = &Os[(w * 32 + lq) * 66];
#pragma unroll
    for (int g = 0; g < 4; ++g) {
      const int d0 = 8 * g + 4 * hi;
      *(unsigned*)&Ow[d0] = pk2(olo[4 * g] * inv, olo[4 * g + 1] * inv);
      *(unsigned*)&Ow[d0 + 2] = pk2(olo[4 * g + 2] * inv, olo[4 * g + 3] * inv);
      *(unsigned*)&Ow[32 + d0] = pk2(ohi[4 * g] * inv, ohi[4 * g + 1] * inv);
      *(unsigned*)&Ow[32 + d0 + 2] = pk2(ohi[4 * g + 2] * inv, ohi[4 * g + 3] * inv);
    }
    __syncthreads();
    for (int s2 = tid; s2 < 1024; s2 += 256) {
      const int wv = s2 >> 8, qq = (s2 >> 3) & 31, sl = (s2 & 7) * 8;
      *(uint4*)&Aout[(qkbase + q0 + wv * 32 + qq) * 64 + sl] =
          *(const uint4*)&Os[(wv * 32 + qq) * 66 + sl];
    }
    __syncthreads();
  }
}

// ---------------------------------------------------------------- diff + RMS
__global__ __launch_bounds__(256) void diff_rms_kernel(
    const u16* __restrict__ A, const float* __restrict__ lq1,
    const float* __restrict__ lk1, const float* __restrict__ lq2,
    const float* __restrict__ lk2, u16* __restrict__ Mb) {
  const int g = threadIdx.x >> 5;          // 0..7 (row within block)
  const int dl = (threadIdx.x & 31) * 2;   // d offset
  const int ridx = blockIdx.x * 8 + g;     // (b,h,t): 0..65535
  const int b = ridx >> 15, rem = ridx & 32767, h = rem >> 11, t = rem & 2047;
  float d1 = 0.f, d2 = 0.f;
#pragma unroll
  for (int i = 0; i < 32; ++i) {
    d1 += lq1[i] * lk1[i];
    d2 += lq2[i] * lk2[i];
  }
  const float lam = expf(d1) - expf(d2) + 0.2f;
  const size_t base1 = ((size_t)(b * 32 + h) * 2048 + t) * 64 + dl;
  const size_t base2 = ((size_t)(b * 32 + 16 + h) * 2048 + t) * 64 + dl;
  const ushort2 a1 = *(const ushort2*)&A[base1];
  const ushort2 a2 = *(const ushort2*)&A[base2];
  const float df0 = bf2f(a1.x) - lam * bf2f(a2.x);
  const float df1 = bf2f(a1.y) - lam * bf2f(a2.y);
  float ss = df0 * df0 + df1 * df1;
  ss += __shfl_xor(ss, 1, 64);
  ss += __shfl_xor(ss, 2, 64);
  ss += __shfl_xor(ss, 4, 64);
  ss += __shfl_xor(ss, 8, 64);
  ss += __shfl_xor(ss, 16, 64);
  const float rms = rsqrtf(ss * (1.0f / 64.0f) + 1e-5f);
  ushort2 o;
  o.x = f2bf(0.8f * df0 * rms);
  o.y = f2bf(0.8f * df1 * rms);
  *(ushort2*)&Mb[((size_t)(b * 2048 + t)) * 1024 + h * 64 + dl] = o;
}

// ---------------------------------------------------------------- launch
extern "C" void kernel_launch(void* const* d_in, const int* in_sizes, int n_in,
                              void* d_out, int out_size, void* d_ws, size_t ws_size,
                              hipStream_t stream) {
  const float* x = (const float*)d_in[0];
  const float* Wa = (const float*)d_in[1];
  const float* Wp = (const float*)d_in[2];
  const float* lq1 = (const float*)d_in[3];
  const float* lk1 = (const float*)d_in[4];
  const float* lq2 = (const float*)d_in[5];
  const float* lk2 = (const float*)d_in[6];
  if (ws_size < (size_t)(64u << 20)) return;  // need 64 MiB scratch

  char* ws = (char*)d_ws;
  u16* Qarr = (u16*)(ws);                        // 8 MiB
  u16* Karr = (u16*)(ws + (8u << 20));           // 8 MiB
  u16* VTarr = (u16*)(ws + (16u << 20));         // 8 MiB
  u16* WpT = (u16*)(ws + (24u << 20));           // 2 MiB
  char* arena = ws + (26u << 20);                // 38 MiB arena
  u16* xb = (u16*)(arena);                       // 8 MiB  (dead after gemm1)
  u16* WaT = (u16*)(arena + (8u << 20));         // 6 MiB  (dead after gemm1)
  u16* qkvb = (u16*)(arena + (14u << 20));       // 24 MiB (dead after vtrans)
  u16* Aout = (u16*)(arena);                     // 16 MiB bf16 (overlays xb/WaT/qkvb-head)
  u16* Mbuf = Qarr;                              // 8 MiB  (overlays Q after attn)

  cvt_f32_bf16<<<4096, 256, 0, stream>>>(x, xb, 1048576);
  transpose_f32_to_bf16<<<dim3(96, 32), 256, 0, stream>>>(Wa, WaT, 1024, 3072);
  transpose_f32_to_bf16<<<dim3(32, 32), 256, 0, stream>>>(Wp, WpT, 1024, 1024);
  gemm_bf16_kernel<true><<<dim3(24, 32), 256, 0, stream>>>(xb, WaT, qkvb, 4096, 3072, 1024);
  rope_kernel<<<4096, 256, 0, stream>>>(qkvb, Qarr, Karr);
  vtrans_kernel<<<dim3(64, 2, 32), 256, 0, stream>>>(qkvb, VTarr);
  attn_kernel<<<dim3(8, 32, 2), 256, 0, stream>>>(Qarr, Karr, VTarr, Aout);
  diff_rms_kernel<<<8192, 256, 0, stream>>>(Aout, lq1, lk1, lq2, lk2, Mbuf);
  gemm_bf16_kernel<false><<<dim3(8, 32), 256, 0, stream>>>(Mbuf, WpT, d_out, 4096, 1024, 1024);
}

// Round 4
// 172.089 us; speedup vs baseline: 2.8218x; 1.0796x over previous
//
#include <hip/hip_runtime.h>

// MultiHeadDiffAttention: B=2, T=2048, C=1024, H=16 (v-heads), 2H=32 (q/k heads),
// D=32, Dv=64. cvt -> transpose weights -> qkv GEMM -> RoPE (Q pre-scaled by
// 1/sqrt(32)*log2e) -> V-transpose -> KV-split swapped-QK^T flash attention
// (exp2-domain softmax, defer-max, MFMA row-sum, permlane P-exchange) ->
// fused merge+diff+RMS -> out GEMM.

typedef unsigned short u16;
typedef __bf16 bf16x8 __attribute__((ext_vector_type(8)));
typedef float f32x4 __attribute__((ext_vector_type(4)));
typedef float f32x16 __attribute__((ext_vector_type(16)));
typedef unsigned u32x2 __attribute__((ext_vector_type(2)));

__device__ __forceinline__ u16 f2bf(float f) {
  return __builtin_bit_cast(u16, (__bf16)f);
}
__device__ __forceinline__ float bf2f(u16 u) {
  return (float)__builtin_bit_cast(__bf16, u);
}
__device__ __forceinline__ unsigned pk2(float a, float b) {
  return (unsigned)f2bf(a) | ((unsigned)f2bf(b) << 16);
}
__device__ __forceinline__ float fmax3(float a, float b, float c) {
  return fmaxf(fmaxf(a, b), c);  // fuses to v_max3_f32
}

// async global->LDS, 16B per lane. LDS dest must be wave-uniform-base + lane*16.
__device__ __forceinline__ void gload16(const u16* g, u16* l) {
  __builtin_amdgcn_global_load_lds(
      (const __attribute__((address_space(1))) unsigned int*)g,
      (__attribute__((address_space(3))) unsigned int*)l, 16, 0, 0);
}

// ---------------------------------------------------------------- cvt x->bf16
__global__ __launch_bounds__(256) void cvt_f32_bf16(const float* __restrict__ in,
                                                    u16* __restrict__ out, int n4) {
  int i = blockIdx.x * 256 + threadIdx.x;
  if (i < n4) {
    float4 v = ((const float4*)in)[i];
    ushort4 o;
    o.x = f2bf(v.x); o.y = f2bf(v.y); o.z = f2bf(v.z); o.w = f2bf(v.w);
    ((ushort4*)out)[i] = o;
  }
}

// ------------------------------------------- transpose fp32 [R][Cn] -> bf16 [Cn][R]
__global__ __launch_bounds__(256) void transpose_f32_to_bf16(
    const float* __restrict__ in, u16* __restrict__ out, int R, int Cn) {
  __shared__ float tile[32][33];
  const int tx = threadIdx.x & 31, ty = threadIdx.x >> 5;  // ty 0..7
  const int c0 = blockIdx.x * 32, r0 = blockIdx.y * 32;
#pragma unroll
  for (int rr = 0; rr < 4; ++rr)
    tile[ty + rr * 8][tx] = in[(size_t)(r0 + ty + rr * 8) * Cn + c0 + tx];
  __syncthreads();
#pragma unroll
  for (int rr = 0; rr < 4; ++rr)
    out[(size_t)(c0 + ty + rr * 8) * R + r0 + tx] = f2bf(tile[tx][ty + rr * 8]);
}

// ---------------------------------------------------------------- bf16 GEMM (m97 style)
// A: [M][K] bf16 row-major; BT: [N][K] bf16; C: [M][N]. 128x128 tile, BK=32.
// XCD-aware block swizzle (grid must be %8==0).
template <bool OUT_BF16>
__global__ __launch_bounds__(256) void gemm_bf16_kernel(
    const u16* __restrict__ A, const u16* __restrict__ BT, void* __restrict__ Cout,
    int Mdim, int Ndim, int Kdim) {
  __shared__ u16 As[128 * 32];
  __shared__ u16 Bs[128 * 32];
  const int tid = threadIdx.x;
  const int l = tid & 63;
  const int w = tid >> 6;
  const int nwgx = gridDim.x;
  const int lin = blockIdx.x + nwgx * blockIdx.y;
  const int cpx = (nwgx * gridDim.y) >> 3;
  const int swz = (lin & 7) * cpx + (lin >> 3);
  const int bm = swz / nwgx, bn = swz % nwgx;
  const int wm = w >> 1, wn = w & 1;
  const int rowA0 = bm * 128, rowB0 = bn * 128;
  const int r_ = tid >> 2;        // 0..63
  const int s_ = (tid & 3) * 8;   // k element offset
  const u16* Ag = &A[(size_t)(rowA0 + r_) * Kdim + s_];
  const u16* Bg = &BT[(size_t)(rowB0 + r_) * Kdim + s_];
  const size_t rstride = (size_t)64 * Kdim;
  f32x4 acc[4][4] = {};
  for (int k0 = 0; k0 < Kdim; k0 += 32) {
    gload16(Ag + k0, &As[r_ * 32 + s_]);
    gload16(Ag + rstride + k0, &As[2048 + r_ * 32 + s_]);
    gload16(Bg + k0, &Bs[r_ * 32 + s_]);
    gload16(Bg + rstride + k0, &Bs[2048 + r_ * 32 + s_]);
    __syncthreads();
    bf16x8 a[4], b[4];
#pragma unroll
    for (int i = 0; i < 4; ++i)
      a[i] = *(const bf16x8*)&As[(wm * 64 + i * 16 + (l & 15)) * 32 + (l >> 4) * 8];
#pragma unroll
    for (int j = 0; j < 4; ++j)
      b[j] = *(const bf16x8*)&Bs[(wn * 64 + j * 16 + (l & 15)) * 32 + (l >> 4) * 8];
#pragma unroll
    for (int i = 0; i < 4; ++i)
#pragma unroll
      for (int j = 0; j < 4; ++j)
        acc[i][j] = __builtin_amdgcn_mfma_f32_16x16x32_bf16(a[i], b[j], acc[i][j], 0, 0, 0);
    __syncthreads();
  }
  const int cr = (l >> 4) * 4;
  const int cc = l & 15;
#pragma unroll
  for (int i = 0; i < 4; ++i)
#pragma unroll
    for (int j = 0; j < 4; ++j)
#pragma unroll
      for (int r = 0; r < 4; ++r) {
        const int row = rowA0 + wm * 64 + i * 16 + cr + r;
        const int col = rowB0 + wn * 64 + j * 16 + cc;
        if (OUT_BF16)
          ((u16*)Cout)[(size_t)row * Ndim + col] = f2bf(acc[i][j][r]);
        else
          ((float*)Cout)[(size_t)row * Ndim + col] = acc[i][j][r];
      }
}

// ---------------------------------------------------------------- RoPE (q,k only)
// Q is pre-scaled by (1/sqrt(32))*log2(e) so attention softmax runs in exp2 domain.
__global__ __launch_bounds__(256) void rope_kernel(const u16* __restrict__ qkv,
                                                   u16* __restrict__ Q,
                                                   u16* __restrict__ K) {
  const int row = blockIdx.x;  // 0..4095
  const int b = row >> 11, t = row & 2047;
  const int tid = threadIdx.x;
  const int isK = tid >> 7, hh = (tid >> 2) & 31, i4 = tid & 3;
  const float qsc = isK ? 1.0f : (0.17677669529663687f * 1.4426950408889634f);
  union { uint4 v; u16 s[8]; } in_, out_;
  in_.v = *(const uint4*)&qkv[(size_t)row * 3072 + isK * 1024 + hh * 32 + i4 * 8];
#pragma unroll
  for (int jj = 0; jj < 4; ++jj) {
    const int i = i4 * 4 + jj;
    const float x1 = bf2f(in_.s[2 * jj]), x2 = bf2f(in_.s[2 * jj + 1]);
    const float theta = exp2f(-0.83048202372184059f * (float)i);  // 10000^(-i/16)
    float sn, cs;
    sincosf((float)t * theta, &sn, &cs);
    out_.s[2 * jj] = f2bf((x1 * cs - x2 * sn) * qsc);
    out_.s[2 * jj + 1] = f2bf((x1 * sn + x2 * cs) * qsc);
  }
  u16* dst = isK ? K : Q;
  *(uint4*)&dst[((size_t)(b * 32 + hh) * 2048 + t) * 32 + i4 * 8] = out_.v;
}

// -------------------------------------- V transpose: qkv v-part -> VT (B,16,64,T)
__global__ __launch_bounds__(256) void vtrans_kernel(const u16* __restrict__ qkv,
                                                     u16* __restrict__ VT) {
  __shared__ u16 tile[32][33];
  const int tx = threadIdx.x & 31, ty = threadIdx.x >> 5;
  const int t0 = blockIdx.x * 32, d0 = blockIdx.y * 32, bh = blockIdx.z;
  const int b = bh >> 4, hv = bh & 15;
#pragma unroll
  for (int k = 0; k < 4; ++k)
    tile[ty + 8 * k][tx] =
        qkv[(size_t)(b * 2048 + t0 + ty + 8 * k) * 3072 + 2048 + hv * 64 + d0 + tx];
  __syncthreads();
#pragma unroll
  for (int k = 0; k < 4; ++k)
    VT[((size_t)bh * 64 + d0 + ty + 8 * k) * 2048 + t0 + tx] = tile[tx][ty + 8 * k];
}

// ---------------------------------------------------------------- flash attention
// Swapped QK^T, 32x32x16 MFMA, exp2-domain. KV-split: block x = (pp, hf); handles
// q-tile pp (range slot=hf) and 15-pp (slot=hf^1); low range = steps [0,qt+1),
// high = [qt+1, 2qt+2). Every block: exactly 17 steps. Grid 1024 blocks, 4/CU.
// Partials: PO[slot] = normalized O (bf16), ML[slot] = (m, l) per q-row.
__global__ __launch_bounds__(256, 4) void attn_kernel(const u16* __restrict__ Q,
                                                      const u16* __restrict__ K,
                                                      const u16* __restrict__ VT,
                                                      u16* __restrict__ PO0,
                                                      u16* __restrict__ PO1,
                                                      float2* __restrict__ ML) {
  __shared__ u16 Ks[64 * 34];       // [k=64][d=32], stride 34 (17-bank step)
  __shared__ u16 Vs[64 * 66];       // [dv=64][k=64], stride 66 (33-bank step)
  __shared__ u16 Os[4 * 32 * 66];   // per-wave O staging
  const int tid = threadIdx.x, l = tid & 63, w = tid >> 6;
  const int pp = blockIdx.x & 7, hf = blockIdx.x >> 3;
  const int h = blockIdx.y, b = blockIdx.z;
  const size_t qkbase = (size_t)(b * 32 + h) * 2048;
  const size_t vtb = (size_t)(b * 16 + (h & 15)) * 64;
  const int lq = l & 31, hi = l >> 5;
  const f32x16 z16 = {};
  const int krow = tid >> 2, ksl = (tid & 3) * 8;   // K tile: 1 uint4/thread
  const int dva = tid >> 3, vsl = (tid & 7) * 8;    // V tile: 2 uint4/thread
  const int dvb = dva + 32;
  const __bf16 one1 = (__bf16)1.0f;
  const bf16x8 ones = {one1, one1, one1, one1, one1, one1, one1, one1};

  for (int halfidx = 0; halfidx < 2; ++halfidx) {
    const int qt = halfidx ? (15 - pp) : pp;
    const int slot = hf ^ halfidx;
    const int s_begin = slot ? (qt + 1) : 0;
    const int s_end = slot ? (2 * qt + 2) : (qt + 1);
    const int q0 = qt * 128;
    const int qw = q0 + w * 32;
    const int q = qw + lq;
    const bf16x8 qf0 = *(const bf16x8*)&Q[(qkbase + q) * 32 + hi * 8];
    const bf16x8 qf1 = *(const bf16x8*)&Q[(qkbase + q) * 32 + 16 + hi * 8];
    f32x16 olo = {}, ohi = {}, lacc = {};
    float mrow = -1e30f;
    // prologue prefetch into regs
    uint4 kreg = *(const uint4*)&K[(qkbase + s_begin * 64 + krow) * 32 + ksl];
    uint4 vreg0 = *(const uint4*)&VT[(vtb + dva) * 2048 + s_begin * 64 + vsl];
    uint4 vreg1 = *(const uint4*)&VT[(vtb + dvb) * 2048 + s_begin * 64 + vsl];
    for (int s = s_begin; s < s_end; ++s) {
      const int kb = s * 64;
      *(uint4*)&Ks[krow * 34 + ksl] = kreg;
      *(uint4*)&Vs[dva * 66 + vsl] = vreg0;
      *(uint4*)&Vs[dvb * 66 + vsl] = vreg1;
      __syncthreads();
      // prefetch next step (overlaps compute); last iter reloads current (benign)
      const int sn = (s + 1 < s_end) ? (s + 1) : s;
      kreg = *(const uint4*)&K[(qkbase + sn * 64 + krow) * 32 + ksl];
      vreg0 = *(const uint4*)&VT[(vtb + dva) * 2048 + sn * 64 + vsl];
      vreg1 = *(const uint4*)&VT[(vtb + dvb) * 2048 + sn * 64 + vsl];
      if (qw + 31 >= kb) {  // wave-uniform skip of fully-masked waves
        // S^T[k][q] = K·Q^T (pre-scaled, exp2 domain)
        f32x16 s0_, s1_;
        {
          const bf16x8 ka0 = *(const bf16x8*)&Ks[lq * 34 + hi * 8];
          const bf16x8 ka1 = *(const bf16x8*)&Ks[lq * 34 + 16 + hi * 8];
          s0_ = __builtin_amdgcn_mfma_f32_32x32x16_bf16(ka0, qf0, z16, 0, 0, 0);
          s0_ = __builtin_amdgcn_mfma_f32_32x32x16_bf16(ka1, qf1, s0_, 0, 0, 0);
          const bf16x8 kc0 = *(const bf16x8*)&Ks[(32 + lq) * 34 + hi * 8];
          const bf16x8 kc1 = *(const bf16x8*)&Ks[(32 + lq) * 34 + 16 + hi * 8];
          s1_ = __builtin_amdgcn_mfma_f32_32x32x16_bf16(kc0, qf0, z16, 0, 0, 0);
          s1_ = __builtin_amdgcn_mfma_f32_32x32x16_bf16(kc1, qf1, s1_, 0, 0, 0);
        }
        const bool nm = (kb + 63 > qw);
        if (nm) {
#pragma unroll
          for (int r = 0; r < 16; ++r) {
            const int kr = (r & 3) + 8 * (r >> 2) + 4 * hi;
            if (kb + kr > q) s0_[r] = -1e30f;
            if (kb + 32 + kr > q) s1_[r] = -1e30f;
          }
        }
        float t16[16];
#pragma unroll
        for (int r = 0; r < 16; ++r) t16[r] = fmaxf(s0_[r], s1_[r]);
        const float m0 = fmax3(t16[0], t16[1], t16[2]);
        const float m1 = fmax3(t16[3], t16[4], t16[5]);
        const float m2 = fmax3(t16[6], t16[7], t16[8]);
        const float m3 = fmax3(t16[9], t16[10], t16[11]);
        const float m4 = fmax3(t16[12], t16[13], t16[14]);
        const float m5 = fmaxf(t16[15], m0);
        const float mB = fmax3(fmax3(m1, m2, m3), m4, m5);
        const float vmax = fmaxf(mB, __shfl_xor(mB, 32, 64));
        // defer-max: only rescale when a row's max grows by >8 (log2 units)
        const float mnew = fmaxf(mrow, vmax);
        if (!__all(vmax <= mrow + 8.0f)) {
          const float sf = __builtin_amdgcn_exp2f(mrow - mnew);
#pragma unroll
          for (int r = 0; r < 16; ++r) {
            olo[r] *= sf; ohi[r] *= sf; lacc[r] *= sf;
          }
          mrow = mnew;
        }
#pragma unroll
        for (int r = 0; r < 16; ++r) {
          s0_[r] = __builtin_amdgcn_exp2f(s0_[r] - mrow);
          s1_[r] = __builtin_amdgcn_exp2f(s1_[r] - mrow);
        }
        // pack P -> bf16 words
        unsigned pw[16];
#pragma unroll
        for (int j = 0; j < 8; ++j) {
          pw[j] = pk2(s0_[2 * j], s0_[2 * j + 1]);
          pw[8 + j] = pk2(s1_[2 * j], s1_[2 * j + 1]);
        }
        // half-exchange -> P^T B-fragments
        bf16x8 pa[4];
#pragma unroll
        for (int fidx = 0; fidx < 4; ++fidx) {
          const unsigned* wt = &pw[fidx * 4];
          union { unsigned u[4]; bf16x8 v; } fr;
#if __has_builtin(__builtin_amdgcn_permlane32_swap)
          const u32x2 rA = __builtin_amdgcn_permlane32_swap(wt[0], wt[2], false, false);
          const u32x2 rB = __builtin_amdgcn_permlane32_swap(wt[1], wt[3], false, false);
          fr.u[0] = rA[0]; fr.u[1] = rB[0]; fr.u[2] = rA[1]; fr.u[3] = rB[1];
#else
          const unsigned ua = hi ? wt[0] : wt[2];
          const unsigned ub = hi ? wt[1] : wt[3];
          const unsigned sa = __shfl_xor(ua, 32, 64);
          const unsigned sb = __shfl_xor(ub, 32, 64);
          fr.u[0] = hi ? sa : wt[0];
          fr.u[1] = hi ? sb : wt[1];
          fr.u[2] = hi ? wt[2] : sa;
          fr.u[3] = hi ? wt[3] : sb;
#endif
          pa[fidx] = fr.v;
        }
        // O^T += V^T·P^T; row-sums via ones-fragment on the MFMA pipe
#pragma unroll
        for (int ks = 0; ks < 4; ++ks) {
          const bf16x8 va = *(const bf16x8*)&Vs[lq * 66 + ks * 16 + hi * 8];
          const bf16x8 vb = *(const bf16x8*)&Vs[(32 + lq) * 66 + ks * 16 + hi * 8];
          olo = __builtin_amdgcn_mfma_f32_32x32x16_bf16(va, pa[ks], olo, 0, 0, 0);
          ohi = __builtin_amdgcn_mfma_f32_32x32x16_bf16(vb, pa[ks], ohi, 0, 0, 0);
          lacc = __builtin_amdgcn_mfma_f32_32x32x16_bf16(ones, pa[ks], lacc, 0, 0, 0);
        }
      }
      __syncthreads();
    }
    // epilogue: write (m,l) + self-normalized partial O (bf16, coalesced)
    const float lsum = lacc[0];
    const float inv = (lsum > 0.f) ? (1.0f / lsum) : 0.f;
    if (hi == 0)
      ML[(size_t)slot * 131072 + qkbase + q] = make_float2(mrow, lsum);
    u16* Ow = &Os[(w * 32 + lq) * 66];
#pragma unroll
    for (int g = 0; g < 4; ++g) {
      const int d0 = 8 * g + 4 * hi;
      *(unsigned*)&Ow[d0] = pk2(olo[4 * g] * inv, olo[4 * g + 1] * inv);
      *(unsigned*)&Ow[d0 + 2] = pk2(olo[4 * g + 2] * inv, olo[4 * g + 3] * inv);
      *(unsigned*)&Ow[32 + d0] = pk2(ohi[4 * g] * inv, ohi[4 * g + 1] * inv);
      *(unsigned*)&Ow[32 + d0 + 2] = pk2(ohi[4 * g + 2] * inv, ohi[4 * g + 3] * inv);
    }
    __syncthreads();
    u16* PO = slot ? PO1 : PO0;
    for (int s2 = tid; s2 < 1024; s2 += 256) {
      const int wv = s2 >> 8, qq = (s2 >> 3) & 31, sl = (s2 & 7) * 8;
      *(uint4*)&PO[(qkbase + q0 + wv * 32 + qq) * 64 + sl] =
          *(const uint4*)&Os[(wv * 32 + qq) * 66 + sl];
    }
    __syncthreads();
  }
}

// ---------------------------------------- fused partial-merge + diff + RMS
__global__ __launch_bounds__(256) void diff_rms_kernel(
    const u16* __restrict__ PO0, const u16* __restrict__ PO1,
    const float2* __restrict__ ML,
    const float* __restrict__ lq1, const float* __restrict__ lk1,
    const float* __restrict__ lq2, const float* __restrict__ lk2,
    u16* __restrict__ Mb) {
  const int g = threadIdx.x >> 5;          // 0..7 (row within block)
  const int dl = (threadIdx.x & 31) * 2;   // d offset
  const int ridx = blockIdx.x * 8 + g;     // (b,h,t): 0..65535
  const int b = ridx >> 15, rem = ridx & 32767, h = rem >> 11, t = rem & 2047;
  float d1 = 0.f, d2 = 0.f;
#pragma unroll
  for (int i = 0; i < 32; ++i) {
    d1 += lq1[i] * lk1[i];
    d2 += lq2[i] * lk2[i];
  }
  const float lam = expf(d1) - expf(d2) + 0.2f;
  const size_t row1 = (size_t)(b * 32 + h) * 2048 + t;
  const size_t row2 = (size_t)(b * 32 + 16 + h) * 2048 + t;
  // merge weights (m in log2 domain)
  const float2 A1 = ML[row1], B1 = ML[131072 + row1];
  const float2 A2 = ML[row2], B2 = ML[131072 + row2];
  const float mm1 = fmaxf(A1.x, B1.x);
  float wa1 = A1.y * __builtin_amdgcn_exp2f(A1.x - mm1);
  float wb1 = B1.y * __builtin_amdgcn_exp2f(B1.x - mm1);
  const float i1 = 1.0f / (wa1 + wb1);
  wa1 *= i1; wb1 *= i1;
  const float mm2 = fmaxf(A2.x, B2.x);
  float wa2 = A2.y * __builtin_amdgcn_exp2f(A2.x - mm2);
  float wb2 = B2.y * __builtin_amdgcn_exp2f(B2.x - mm2);
  const float i2 = 1.0f / (wa2 + wb2);
  wa2 *= i2; wb2 *= i2;
  const ushort2 p01 = *(const ushort2*)&PO0[row1 * 64 + dl];
  const ushort2 p11 = *(const ushort2*)&PO1[row1 * 64 + dl];
  const ushort2 p02 = *(const ushort2*)&PO0[row2 * 64 + dl];
  const ushort2 p12 = *(const ushort2*)&PO1[row2 * 64 + dl];
  const float a1x = wa1 * bf2f(p01.x) + wb1 * bf2f(p11.x);
  const float a1y = wa1 * bf2f(p01.y) + wb1 * bf2f(p11.y);
  const float a2x = wa2 * bf2f(p02.x) + wb2 * bf2f(p12.x);
  const float a2y = wa2 * bf2f(p02.y) + wb2 * bf2f(p12.y);
  const float df0 = a1x - lam * a2x;
  const float df1 = a1y - lam * a2y;
  float ss = df0 * df0 + df1 * df1;
  ss += __shfl_xor(ss, 1, 64);
  ss += __shfl_xor(ss, 2, 64);
  ss += __shfl_xor(ss, 4, 64);
  ss += __shfl_xor(ss, 8, 64);
  ss += __shfl_xor(ss, 16, 64);
  const float rms = rsqrtf(ss * (1.0f / 64.0f) + 1e-5f);
  ushort2 o;
  o.x = f2bf(0.8f * df0 * rms);
  o.y = f2bf(0.8f * df1 * rms);
  *(ushort2*)&Mb[((size_t)(b * 2048 + t)) * 1024 + h * 64 + dl] = o;
}

// ---------------------------------------------------------------- launch
extern "C" void kernel_launch(void* const* d_in, const int* in_sizes, int n_in,
                              void* d_out, int out_size, void* d_ws, size_t ws_size,
                              hipStream_t stream) {
  const float* x = (const float*)d_in[0];
  const float* Wa = (const float*)d_in[1];
  const float* Wp = (const float*)d_in[2];
  const float* lq1 = (const float*)d_in[3];
  const float* lk1 = (const float*)d_in[4];
  const float* lq2 = (const float*)d_in[5];
  const float* lk2 = (const float*)d_in[6];
  if (ws_size < (size_t)(64u << 20)) return;  // need 64 MiB scratch

  char* ws = (char*)d_ws;
  u16* Qarr = (u16*)(ws);                        // 8 MiB
  u16* Karr = (u16*)(ws + (8u << 20));           // 8 MiB
  u16* VTarr = (u16*)(ws + (16u << 20));         // 8 MiB
  u16* WpT = (u16*)(ws + (24u << 20));           // 2 MiB
  char* arena = ws + (26u << 20);                // 38 MiB arena
  u16* xb = (u16*)(arena);                       // 8 MiB  (dead after gemm1)
  u16* WaT = (u16*)(arena + (8u << 20));         // 6 MiB  (dead after gemm1)
  u16* qkvb = (u16*)(arena + (14u << 20));       // 24 MiB (dead after vtrans)
  u16* PO0 = (u16*)(arena);                      // 16 MiB partial O (slot 0)
  u16* PO1 = (u16*)(arena + (16u << 20));        // 16 MiB partial O (slot 1)
  float2* ML = (float2*)(arena + (32u << 20));   // 2 MiB (m,l) per row per slot
  u16* Mbuf = Qarr;                              // 8 MiB (overlays Q after attn)

  cvt_f32_bf16<<<4096, 256, 0, stream>>>(x, xb, 1048576);
  transpose_f32_to_bf16<<<dim3(96, 32), 256, 0, stream>>>(Wa, WaT, 1024, 3072);
  transpose_f32_to_bf16<<<dim3(32, 32), 256, 0, stream>>>(Wp, WpT, 1024, 1024);
  gemm_bf16_kernel<true><<<dim3(24, 32), 256, 0, stream>>>(xb, WaT, qkvb, 4096, 3072, 1024);
  rope_kernel<<<4096, 256, 0, stream>>>(qkvb, Qarr, Karr);
  vtrans_kernel<<<dim3(64, 2, 32), 256, 0, stream>>>(qkvb, VTarr);
  attn_kernel<<<dim3(16, 32, 2), 256, 0, stream>>>(Qarr, Karr, VTarr, PO0, PO1, ML);
  diff_rms_kernel<<<8192, 256, 0, stream>>>(PO0, PO1, ML, lq1, lk1, lq2, lk2, Mbuf);
  gemm_bf16_kernel<false><<<dim3(8, 32), 256, 0, stream>>>(Mbuf, WpT, d_out, 4096, 1024, 1024);
}